// Round 1
// baseline (8735.577 us; speedup 1.0000x reference)
//
#include <hip/hip_runtime.h>

// DRNN: 4-layer dilated LSTM, T=2048, dil {1,2,4,8}, dims 256->128->128->128->256.
// Strategy: kernel 1 precomputes Wih0@x+biases (parallel GEMM). Kernel 2 is a
// persistent 45-block wavefront pipeline: 1 block for layer0 (dil 1, sequential),
// then per-layer chain blocks (one chain per dilation phase, recurrent state local)
// with element-splits where weights exceed register capacity (L1/L2: 2 halves,
// L3: 4 quarters). Cross-block communication: relaxed agent atomics for data,
// release/acquire agent atomics for monotonic progress flags. Flags are offset by
// FB so 0x00000000 and 0xAAAAAAAA initial states both read as "not ready".
// All spins carry a budget so failure modes are wrong-answer, never hang.

#define TSTEPS 2048
#define FB 1048576

// ws layout in floats
#define ZX_OFF 0
#define Y0_OFF (TSTEPS * 512)
#define Y1_OFF (Y0_OFF + TSTEPS * 128)
#define Y2_OFF (Y1_OFF + TSTEPS * 128)
#define FLAG_OFF (Y2_OFF + TSTEPS * 128)

__device__ __forceinline__ float f_sig(float x) { return 1.0f / (1.0f + __expf(-x)); }
__device__ __forceinline__ float f_tanh(float x) {
  float xc = fminf(fmaxf(x, -15.0f), 15.0f);
  float e = __expf(2.0f * xc);
  return (e - 1.0f) / (e + 1.0f);
}
__device__ __forceinline__ float g_load(const float* p) {
  return __hip_atomic_load((float*)p, __ATOMIC_RELAXED, __HIP_MEMORY_SCOPE_AGENT);
}
__device__ __forceinline__ void g_store(float* p, float v) {
  __hip_atomic_store(p, v, __ATOMIC_RELAXED, __HIP_MEMORY_SCOPE_AGENT);
}
__device__ __forceinline__ int fl_load(int* p) {
  return __hip_atomic_load(p, __ATOMIC_ACQUIRE, __HIP_MEMORY_SCOPE_AGENT);
}
__device__ __forceinline__ void fl_store(int* p, int v) {
  __hip_atomic_store(p, v, __ATOMIC_RELEASE, __HIP_MEMORY_SCOPE_AGENT);
}

// ---------------- kernel 1: zx[j][r] = Wih0[r,:]@x[j,:] + bih0[r] + bhh0[r] ----
__global__ __launch_bounds__(256) void zx0_kernel(
    const float* __restrict__ x, const float* __restrict__ Wih0,
    const float* __restrict__ bih0, const float* __restrict__ bhh0,
    float* __restrict__ zx) {
  __shared__ float xs[4 * 256];
  const int t = threadIdx.x;
  const int j0 = blockIdx.x * 4;
  ((float4*)xs)[t] = ((const float4*)(x + j0 * 256))[t];
  __syncthreads();
  const int r0 = t, r1 = t + 256;
  float a0[4] = {0, 0, 0, 0}, a1[4] = {0, 0, 0, 0};
  const float* w0p = Wih0 + r0 * 256;
  const float* w1p = Wih0 + r1 * 256;
#pragma unroll 8
  for (int k = 0; k < 256; k += 4) {
    float4 wa = *(const float4*)(w0p + k);
    float4 wb = *(const float4*)(w1p + k);
#pragma unroll
    for (int jj = 0; jj < 4; jj++) {
      float4 xv = *(const float4*)(xs + jj * 256 + k);
      a0[jj] += wa.x * xv.x + wa.y * xv.y + wa.z * xv.z + wa.w * xv.w;
      a1[jj] += wb.x * xv.x + wb.y * xv.y + wb.z * xv.z + wb.w * xv.w;
    }
  }
  float b0 = bih0[r0] + bhh0[r0];
  float b1 = bih0[r1] + bhh0[r1];
#pragma unroll
  for (int jj = 0; jj < 4; jj++) {
    zx[(j0 + jj) * 512 + r0] = a0[jj] + b0;
    zx[(j0 + jj) * 512 + r1] = a1[jj] + b1;
  }
}

// ---------------- stage 0: layer 0, dilation 1, one block, 256 thr -------------
__device__ void lstm_stage0(int t, const float* __restrict__ Whh0,
                            const float* __restrict__ h00, const float* __restrict__ c00,
                            const float* __restrict__ zx, float* __restrict__ y0,
                            int* __restrict__ F, float* LDS) {
  float* hl = LDS;        // [128]
  float* zl = LDS + 128;  // [512]
  float w0[128], w1[128];
#pragma unroll
  for (int k = 0; k < 128; k += 4) {
    float4 a = *(const float4*)(Whh0 + t * 128 + k);
    w0[k] = a.x; w0[k + 1] = a.y; w0[k + 2] = a.z; w0[k + 3] = a.w;
    float4 b = *(const float4*)(Whh0 + (t + 256) * 128 + k);
    w1[k] = b.x; w1[k + 1] = b.y; w1[k + 2] = b.z; w1[k + 3] = b.w;
  }
  float c = 0.0f, hpend = 0.0f;
  if (t < 128) { hl[t] = h00[t]; c = c00[t]; }
  __syncthreads();
  float zxa = zx[t], zxb = zx[t + 256];
  for (int j = 0; j < TSTEPS; j++) {
    if (j > 0 && t < 128) g_store(y0 + (j - 1) * 128 + t, hpend);  // deferred store
    float za = zxa, zb = zxb;
    if (j + 1 < TSTEPS) {  // prefetch next precomputed input
      zxa = zx[(j + 1) * 512 + t];
      zxb = zx[(j + 1) * 512 + t + 256];
    }
    float a0 = 0, a1 = 0, a2 = 0, a3 = 0, b0 = 0, b1 = 0, b2 = 0, b3 = 0;
#pragma unroll
    for (int k = 0; k < 128; k += 4) {
      float4 hv = *(const float4*)(hl + k);
      a0 += w0[k] * hv.x; a1 += w0[k + 1] * hv.y;
      a2 += w0[k + 2] * hv.z; a3 += w0[k + 3] * hv.w;
      b0 += w1[k] * hv.x; b1 += w1[k + 1] * hv.y;
      b2 += w1[k + 2] * hv.z; b3 += w1[k + 3] * hv.w;
    }
    zl[t] = za + ((a0 + a1) + (a2 + a3));
    zl[t + 256] = zb + ((b0 + b1) + (b2 + b3));
    __syncthreads();  // drains deferred store too
    if (t == 0 && j > 0) fl_store(F, FB + j - 1);
    if (t < 128) {
      float ig = f_sig(zl[t]), fg = f_sig(zl[t + 128]);
      float gg = f_tanh(zl[t + 256]), og = f_sig(zl[t + 384]);
      c = fg * c + ig * gg;
      float h2 = og * f_tanh(c);
      hpend = h2;
      hl[t] = h2;
    }
    __syncthreads();
  }
  if (t < 128) g_store(y0 + (TSTEPS - 1) * 128 + t, hpend);
  __syncthreads();
  if (t == 0) fl_store(F, FB + TSTEPS - 1);
}

// ------- stages 1/2: chain q (dil D), element half p, 256 thr, thread-per-row --
template <int D, bool TWO_IN>
__device__ void lstm_stage_mid(int q, int p, int t,
                               const float* __restrict__ Wih, const float* __restrict__ Whh,
                               const float* __restrict__ bih, const float* __restrict__ bhh,
                               const float* __restrict__ h0s, const float* __restrict__ c0s,
                               const float* __restrict__ yin, float* __restrict__ yout,
                               int* __restrict__ F, int in0, int in1, int my, int peer,
                               float* LDS) {
  float* vb0 = LDS;        float* vb1 = LDS + 128;
  float* hb0 = LDS + 256;  float* hb1 = LDS + 384;
  float* zl = LDS + 512;   // [256]
  const int g = t >> 6, le = t & 63;
  const int gr = g * 128 + p * 64 + le;
  float wih[128], whh[128];
#pragma unroll
  for (int k = 0; k < 128; k += 4) {
    float4 a = *(const float4*)(Wih + gr * 128 + k);
    wih[k] = a.x; wih[k + 1] = a.y; wih[k + 2] = a.z; wih[k + 3] = a.w;
    float4 b = *(const float4*)(Whh + gr * 128 + k);
    whh[k] = b.x; whh[k + 1] = b.y; whh[k + 2] = b.z; whh[k + 3] = b.w;
  }
  const float bsum = bih[gr] + bhh[gr];
  float c = (t < 64) ? c0s[q * 128 + p * 64 + t] : 0.0f;
  if (t < 128) hb0[t] = h0s[q * 128 + t];
  int bud = 1 << 19;
  int pf0 = fl_load(F + in0 * 16);
  int pf1 = TWO_IN ? fl_load(F + in1 * 16) : 0x7fffffff;
  int pfp = fl_load(F + peer * 16);
  while (pf0 < FB + q) { if (--bud < 0) break; pf0 = fl_load(F + in0 * 16); }
  if (TWO_IN) while (pf1 < FB + q) { if (--bud < 0) break; pf1 = fl_load(F + in1 * 16); }
  if (t < 128) vb0[t] = g_load(yin + q * 128 + t);
  __syncthreads();
  const int NS = TSTEPS / D;
  for (int s = 0; s < NS; s++) {
    const int j = q + s * D;
    float* vc = (s & 1) ? vb1 : vb0;
    float* hc = (s & 1) ? hb1 : hb0;
    float* va = (s & 1) ? vb0 : vb1;
    float* ha = (s & 1) ? hb0 : hb1;
    float a0 = 0, a1 = 0, a2 = 0, a3 = 0;
#pragma unroll
    for (int k = 0; k < 128; k += 4) {
      float4 vv = *(const float4*)(vc + k);
      a0 += wih[k] * vv.x; a1 += wih[k + 1] * vv.y;
      a2 += wih[k + 2] * vv.z; a3 += wih[k + 3] * vv.w;
    }
#pragma unroll
    for (int k = 0; k < 128; k += 4) {
      float4 hv = *(const float4*)(hc + k);
      a0 += whh[k] * hv.x; a1 += whh[k + 1] * hv.y;
      a2 += whh[k + 2] * hv.z; a3 += whh[k + 3] * hv.w;
    }
    zl[t] = bsum + ((a0 + a1) + (a2 + a3));
    __syncthreads();
    float h2 = 0.0f;
    if (t < 64) {
      float ig = f_sig(zl[t]), fg = f_sig(zl[64 + t]);
      float gg = f_tanh(zl[128 + t]), og = f_sig(zl[192 + t]);
      c = fg * c + ig * gg;
      h2 = og * f_tanh(c);
      g_store(yout + j * 128 + p * 64 + t, h2);  // peer + downstream need this now
      ha[p * 64 + t] = h2;                       // own half of next-step h
    }
    __syncthreads();  // drains the yout store
    if (t == 0) fl_store(F + my * 16, FB + j);
    pfp = fl_load(F + peer * 16);  // early re-poll: peer released ~now
    if (s + 1 < NS) {
      const int j2 = j + D;
      while (pfp < FB + j) { if (--bud < 0) break; pfp = fl_load(F + peer * 16); }
      if (t >= 64 && t < 128) {
        int pe = (1 - p) * 64 + (t - 64);
        ha[pe] = g_load(yout + j * 128 + pe);  // peer half of h(j)
      }
      while (pf0 < FB + j2) { if (--bud < 0) break; pf0 = fl_load(F + in0 * 16); }
      if (TWO_IN) while (pf1 < FB + j2) { if (--bud < 0) break; pf1 = fl_load(F + in1 * 16); }
      if (t >= 128) va[t - 128] = g_load(yin + j2 * 128 + (t - 128));  // next v
      pf0 = fl_load(F + in0 * 16);  // prefetch for next iteration
      if (TWO_IN) pf1 = fl_load(F + in1 * 16);
      pfp = fl_load(F + peer * 16);
    }
    __syncthreads();
  }
}

// ------- stage 3: chain q (dil 8), element quarter p, dh=256, writes d_out -----
__device__ void lstm_stage3(int q, int p, int t,
                            const float* __restrict__ Wih3, const float* __restrict__ Whh3,
                            const float* __restrict__ bih3, const float* __restrict__ bhh3,
                            const float* __restrict__ h03, const float* __restrict__ c03,
                            const float* __restrict__ yin, float* __restrict__ out,
                            int* __restrict__ F, int in0, int in1, int my,
                            int pe0, int pe1, int pe2, float* LDS) {
  float* vb0 = LDS;        float* vb1 = LDS + 128;
  float* hb0 = LDS + 256;  float* hb1 = LDS + 512;
  float* zl = LDS + 768;   // [256]
  const int g = t >> 6, le = t & 63;
  const int gr = g * 256 + p * 64 + le;
  float wih[128], whh[256];
#pragma unroll
  for (int k = 0; k < 128; k += 4) {
    float4 a = *(const float4*)(Wih3 + gr * 128 + k);
    wih[k] = a.x; wih[k + 1] = a.y; wih[k + 2] = a.z; wih[k + 3] = a.w;
  }
#pragma unroll
  for (int k = 0; k < 256; k += 4) {
    float4 b = *(const float4*)(Whh3 + gr * 256 + k);
    whh[k] = b.x; whh[k + 1] = b.y; whh[k + 2] = b.z; whh[k + 3] = b.w;
  }
  const float bsum = bih3[gr] + bhh3[gr];
  float c = (t < 64) ? c03[q * 256 + p * 64 + t] : 0.0f;
  hb0[t] = h03[q * 256 + t];
  int bud = 1 << 19;
  int pf0 = fl_load(F + in0 * 16), pf1 = fl_load(F + in1 * 16);
  int pp0 = fl_load(F + pe0 * 16), pp1 = fl_load(F + pe1 * 16), pp2 = fl_load(F + pe2 * 16);
  while (pf0 < FB + q) { if (--bud < 0) break; pf0 = fl_load(F + in0 * 16); }
  while (pf1 < FB + q) { if (--bud < 0) break; pf1 = fl_load(F + in1 * 16); }
  if (t < 128) vb0[t] = g_load(yin + q * 128 + t);
  __syncthreads();
  for (int s = 0; s < 256; s++) {
    const int j = q + 8 * s;
    float* vc = (s & 1) ? vb1 : vb0;
    float* hc = (s & 1) ? hb1 : hb0;
    float* va = (s & 1) ? vb0 : vb1;
    float* ha = (s & 1) ? hb0 : hb1;
    float a0 = 0, a1 = 0, a2 = 0, a3 = 0;
#pragma unroll
    for (int k = 0; k < 128; k += 4) {
      float4 vv = *(const float4*)(vc + k);
      a0 += wih[k] * vv.x; a1 += wih[k + 1] * vv.y;
      a2 += wih[k + 2] * vv.z; a3 += wih[k + 3] * vv.w;
    }
#pragma unroll
    for (int k = 0; k < 256; k += 4) {
      float4 hv = *(const float4*)(hc + k);
      a0 += whh[k] * hv.x; a1 += whh[k + 1] * hv.y;
      a2 += whh[k + 2] * hv.z; a3 += whh[k + 3] * hv.w;
    }
    zl[t] = bsum + ((a0 + a1) + (a2 + a3));
    __syncthreads();
    if (t < 64) {
      float ig = f_sig(zl[t]), fg = f_sig(zl[64 + t]);
      float gg = f_tanh(zl[128 + t]), og = f_sig(zl[192 + t]);
      c = fg * c + ig * gg;
      float h2 = og * f_tanh(c);
      g_store(out + j * 256 + p * 64 + t, h2);  // final output; peers read as h hist
      ha[p * 64 + t] = h2;
    }
    __syncthreads();
    if (t == 0) fl_store(F + my * 16, FB + j);
    pp0 = fl_load(F + pe0 * 16); pp1 = fl_load(F + pe1 * 16); pp2 = fl_load(F + pe2 * 16);
    if (s + 1 < 256) {
      const int j2 = j + 8;
      while (pp0 < FB + j) { if (--bud < 0) break; pp0 = fl_load(F + pe0 * 16); }
      while (pp1 < FB + j) { if (--bud < 0) break; pp1 = fl_load(F + pe1 * 16); }
      while (pp2 < FB + j) { if (--bud < 0) break; pp2 = fl_load(F + pe2 * 16); }
      if (t >= 64) {
        int u = t - 64;
        int pe = (u < p * 64) ? u : u + 64;  // skip own quarter
        ha[pe] = g_load(out + j * 256 + pe);
      }
      while (pf0 < FB + j2) { if (--bud < 0) break; pf0 = fl_load(F + in0 * 16); }
      while (pf1 < FB + j2) { if (--bud < 0) break; pf1 = fl_load(F + in1 * 16); }
      if (t < 64) {
        va[t] = g_load(yin + j2 * 128 + t);
        va[t + 64] = g_load(yin + j2 * 128 + t + 64);
      }
      pf0 = fl_load(F + in0 * 16); pf1 = fl_load(F + in1 * 16);
      pp0 = fl_load(F + pe0 * 16); pp1 = fl_load(F + pe1 * 16); pp2 = fl_load(F + pe2 * 16);
    }
    __syncthreads();
  }
}

// ---------------- persistent pipeline kernel -----------------------------------
__global__ __launch_bounds__(256, 1) void drnn_kernel(
    const float* __restrict__ Whh0, const float* __restrict__ h00, const float* __restrict__ c00,
    const float* __restrict__ Wih1, const float* __restrict__ Whh1,
    const float* __restrict__ bih1, const float* __restrict__ bhh1,
    const float* __restrict__ h01, const float* __restrict__ c01,
    const float* __restrict__ Wih2, const float* __restrict__ Whh2,
    const float* __restrict__ bih2, const float* __restrict__ bhh2,
    const float* __restrict__ h02, const float* __restrict__ c02,
    const float* __restrict__ Wih3, const float* __restrict__ Whh3,
    const float* __restrict__ bih3, const float* __restrict__ bhh3,
    const float* __restrict__ h03, const float* __restrict__ c03,
    const float* __restrict__ zx, float* __restrict__ y0, float* __restrict__ y1,
    float* __restrict__ y2, int* __restrict__ F, float* __restrict__ out) {
  __shared__ float LDS[1024];
  const int b = blockIdx.x;
  const int t = threadIdx.x;
  if (b == 0) {
    lstm_stage0(t, Whh0, h00, c00, zx, y0, F, LDS);
    return;
  }
  if (b <= 4) {  // stage 1: flags 1..4, input flag 0
    int i = b - 1, q = i >> 1, p = i & 1;
    lstm_stage_mid<2, false>(q, p, t, Wih1, Whh1, bih1, bhh1, h01, c01, y0, y1, F,
                             0, 0, 1 + q * 2 + p, 1 + q * 2 + (1 - p), LDS);
    return;
  }
  if (b <= 12) {  // stage 2: flags 5..12, inputs f1[q&1][0..1]
    int i = b - 5, q = i >> 1, p = i & 1;
    int cin = q & 1;
    lstm_stage_mid<4, true>(q, p, t, Wih2, Whh2, bih2, bhh2, h02, c02, y1, y2, F,
                            1 + cin * 2 + 0, 1 + cin * 2 + 1,
                            5 + q * 2 + p, 5 + q * 2 + (1 - p), LDS);
    return;
  }
  {  // stage 3: flags 13..44, inputs f2[q&3][0..1]
    int i = b - 13, q = i >> 2, p = i & 3;
    int cin = q & 3;
    int base = 13 + q * 4;
    int pe[3], w = 0;
    for (int pp = 0; pp < 4; pp++)
      if (pp != p) pe[w++] = base + pp;
    lstm_stage3(q, p, t, Wih3, Whh3, bih3, bhh3, h03, c03, y2, out, F,
                5 + cin * 2 + 0, 5 + cin * 2 + 1, base + p, pe[0], pe[1], pe[2], LDS);
  }
}

extern "C" void kernel_launch(void* const* d_in, const int* in_sizes, int n_in,
                              void* d_out, int out_size, void* d_ws, size_t ws_size,
                              hipStream_t stream) {
  const float* x    = (const float*)d_in[0];
  const float* Wih0 = (const float*)d_in[1];
  const float* Whh0 = (const float*)d_in[2];
  const float* bih0 = (const float*)d_in[3];
  const float* bhh0 = (const float*)d_in[4];
  const float* h00  = (const float*)d_in[5];
  const float* c00  = (const float*)d_in[6];
  const float* Wih1 = (const float*)d_in[7];
  const float* Whh1 = (const float*)d_in[8];
  const float* bih1 = (const float*)d_in[9];
  const float* bhh1 = (const float*)d_in[10];
  const float* h01  = (const float*)d_in[11];
  const float* c01  = (const float*)d_in[12];
  const float* Wih2 = (const float*)d_in[13];
  const float* Whh2 = (const float*)d_in[14];
  const float* bih2 = (const float*)d_in[15];
  const float* bhh2 = (const float*)d_in[16];
  const float* h02  = (const float*)d_in[17];
  const float* c02  = (const float*)d_in[18];
  const float* Wih3 = (const float*)d_in[19];
  const float* Whh3 = (const float*)d_in[20];
  const float* bih3 = (const float*)d_in[21];
  const float* bhh3 = (const float*)d_in[22];
  const float* h03  = (const float*)d_in[23];
  const float* c03  = (const float*)d_in[24];

  float* ws = (float*)d_ws;
  float* zx = ws + ZX_OFF;
  float* y0 = ws + Y0_OFF;
  float* y1 = ws + Y1_OFF;
  float* y2 = ws + Y2_OFF;
  int* F    = (int*)(ws + FLAG_OFF);
  float* out = (float*)d_out;

  zx0_kernel<<<512, 256, 0, stream>>>(x, Wih0, bih0, bhh0, zx);
  drnn_kernel<<<45, 256, 0, stream>>>(Whh0, h00, c00,
                                      Wih1, Whh1, bih1, bhh1, h01, c01,
                                      Wih2, Whh2, bih2, bhh2, h02, c02,
                                      Wih3, Whh3, bih3, bhh3, h03, c03,
                                      zx, y0, y1, y2, F, out);
}